// Round 1
// baseline (240.802 us; speedup 1.0000x reference)
//
#include <hip/hip_runtime.h>
#include <stdint.h>

#define DIM   128
#define KCOLS 65536
#define BB    1024
#define LL    512
#define PSZ   8388608
#define INV_T (1.0f / 0.09f)
#define MOM   0.7f

// output layout (float32 elements, concatenated in return order)
#define OUT_LOGITS 0
#define OUT_LABELS (BB * LL)                    // 524288
#define OUT_QUEUE  (BB * LL + BB)               // 525312
#define OUT_PARAMK (BB * LL + BB + DIM * KCOLS) // 8913920

// ws layout (bytes)
#define WS_QT 0                         // bf16 queueT [KCOLS][DIM] = 16 MiB
#define WS_QN (KCOLS * DIM * 2)         // f32 normalized q [BB][DIM]
#define WS_KN (WS_QN + BB * DIM * 4)    // f32 normalized keys [BB][DIM]

__device__ inline unsigned short f32_to_bf16(float f) {
    uint32_t u = __float_as_uint(f);
    uint32_t r = (u + 0x7fffu + ((u >> 16) & 1u)) >> 16;
    return (unsigned short)r;
}

// one wave per row; rows 0..BB-1 = q -> qn (normalized), BB..2BB-1 = keys -> kn
__global__ void norm_kernel(const float* __restrict__ q,
                            const float* __restrict__ keys,
                            float* __restrict__ qn, float* __restrict__ kn) {
    int w    = threadIdx.x >> 6;
    int lane = threadIdx.x & 63;
    int row  = blockIdx.x * 4 + w;   // 0..2047
    const float* src;
    float* dst;
    int r;
    if (row < BB) { src = q;    dst = qn; r = row; }
    else          { src = keys; dst = kn; r = row - BB; }
    float2 v = *(const float2*)&src[r * DIM + lane * 2];
    float s  = v.x * v.x + v.y * v.y;
#pragma unroll
    for (int m = 32; m >= 1; m >>= 1) s += __shfl_xor(s, m, 64);
    float inv = 1.0f / sqrtf(s);
    float2 o  = {v.x * inv, v.y * inv};
    *(float2*)&dst[r * DIM + lane * 2] = o;
}

// new_param_k = MOM*param_k + (1-MOM)*param_q ; also writes labels (zeros)
__global__ void param_kernel(const float* __restrict__ pq,
                             const float* __restrict__ pk,
                             float* __restrict__ out) {
    int gid  = blockIdx.x * blockDim.x + threadIdx.x;
    float4 a = ((const float4*)pq)[gid];
    float4 b = ((const float4*)pk)[gid];
    float4 r;
    r.x = b.x * MOM + a.x * (1.0f - MOM);
    r.y = b.y * MOM + a.y * (1.0f - MOM);
    r.z = b.z * MOM + a.z * (1.0f - MOM);
    r.w = b.w * MOM + a.w * (1.0f - MOM);
    ((float4*)(out + OUT_PARAMK))[gid] = r;
    if (gid < BB) out[OUT_LABELS + gid] = 0.0f;
}

// new_queue = queue with columns [start, start+BB) replaced by kn^T
__global__ void queue_kernel(const float* __restrict__ queue,
                             const float* __restrict__ kn,
                             const int* __restrict__ ptr_p,
                             float* __restrict__ outq) {
    int gid  = blockIdx.x * blockDim.x + threadIdx.x;
    int f    = gid * 4;
    float4 v = ((const float4*)queue)[gid];
    int d    = f >> 16;          // f / KCOLS
    int k    = f & (KCOLS - 1);  // f % KCOLS
    int ptr  = ptr_p[0];
    int start = min(max(ptr, 0), KCOLS - BB);  // dynamic_update_slice clamps
    if (k + 3 >= start && k < start + BB) {
        float vv[4] = {v.x, v.y, v.z, v.w};
#pragma unroll
        for (int j = 0; j < 4; ++j) {
            int c = k + j;
            if (c >= start && c < start + BB) vv[j] = kn[(c - start) * DIM + d];
        }
        v.x = vv[0]; v.y = vv[1]; v.z = vv[2]; v.w = vv[3];
    }
    ((float4*)outq)[gid] = v;
}

// queue [DIM][KCOLS] f32  ->  qt [KCOLS][DIM] bf16
__global__ void transpose_kernel(const float* __restrict__ queue,
                                 unsigned short* __restrict__ qt) {
    __shared__ float tile[64][DIM + 1];
    int k0 = blockIdx.x * 64;
    int t  = threadIdx.x;
    int kk = t & 63, dq = t >> 6;  // dq 0..3
#pragma unroll
    for (int i = 0; i < 32; ++i) {
        int d = i * 4 + dq;
        tile[kk][d] = queue[d * KCOLS + k0 + kk];
    }
    __syncthreads();
    int lane16 = t & 15, kq = t >> 4;  // kq 0..15
#pragma unroll
    for (int ki = 0; ki < 4; ++ki) {
        int kl = kq + ki * 16;
#pragma unroll
        for (int seg = 0; seg < 4; ++seg) {
            int d0 = seg * 32 + lane16 * 2;
            uint32_t lo = (uint32_t)f32_to_bf16(tile[kl][d0]);
            uint32_t hi = (uint32_t)f32_to_bf16(tile[kl][d0 + 1]);
            *(uint32_t*)&qt[(size_t)(k0 + kl) * DIM + d0] = lo | (hi << 16);
        }
    }
}

// logits[b][l] = dot(qn[b], queueT[sample_idx[b][l]]) / T
// one wave per dot; 4 waves/block, 8 l per wave
__global__ void logits_kernel(const float* __restrict__ qn,
                              const unsigned short* __restrict__ qt,
                              const int* __restrict__ sidx,
                              float* __restrict__ out_logits) {
    int b    = blockIdx.y;
    int w    = threadIdx.x >> 6;
    int lane = threadIdx.x & 63;
    float2 qv = *(const float2*)&qn[b * DIM + lane * 2];
    int l0 = blockIdx.x * 32 + w * 8;
#pragma unroll
    for (int j = 0; j < 8; ++j) {
        int l   = l0 + j;
        int idx = sidx[b * LL + l];
        uint32_t u = *(const uint32_t*)&qt[(size_t)idx * DIM + lane * 2];
        float c0 = __uint_as_float(u << 16);
        float c1 = __uint_as_float(u & 0xffff0000u);
        float s  = qv.x * c0 + qv.y * c1;
#pragma unroll
        for (int m = 32; m >= 1; m >>= 1) s += __shfl_xor(s, m, 64);
        if (lane == 0) out_logits[b * LL + l] = s * INV_T;
    }
}

extern "C" void kernel_launch(void* const* d_in, const int* in_sizes, int n_in,
                              void* d_out, int out_size, void* d_ws, size_t ws_size,
                              hipStream_t stream) {
    const float* q     = (const float*)d_in[0];
    const float* queue = (const float*)d_in[1];
    const float* keys  = (const float*)d_in[2];
    const float* pq    = (const float*)d_in[3];
    const float* pk    = (const float*)d_in[4];
    const int*   sidx  = (const int*)d_in[5];
    const int*   ptr_p = (const int*)d_in[6];
    float* out = (float*)d_out;

    unsigned short* ws_qt = (unsigned short*)((char*)d_ws + WS_QT);
    float* ws_qn = (float*)((char*)d_ws + WS_QN);
    float* ws_kn = (float*)((char*)d_ws + WS_KN);

    // 1) row norms: qn, kn
    norm_kernel<<<512, 256, 0, stream>>>(q, keys, ws_qn, ws_kn);
    // 2) momentum param update + labels
    param_kernel<<<PSZ / 4 / 256, 256, 0, stream>>>(pq, pk, out);
    // 3) queue copy + circular overwrite
    queue_kernel<<<(DIM * KCOLS) / 4 / 256, 256, 0, stream>>>(queue, ws_kn, ptr_p,
                                                              out + OUT_QUEUE);
    // 4) transpose queue -> bf16 queueT
    transpose_kernel<<<KCOLS / 64, 256, 0, stream>>>(queue, ws_qt);
    // 5) gathered dot products
    logits_kernel<<<dim3(LL / 32, BB), 256, 0, stream>>>(ws_qn, ws_qt, sidx,
                                                         out + OUT_LOGITS);
}

// Round 2
// 213.471 us; speedup vs baseline: 1.1280x; 1.1280x over previous
//
#include <hip/hip_runtime.h>
#include <stdint.h>

#define DIM   128
#define KCOLS 65536
#define BB    1024
#define LL    512
#define PSZ   8388608
#define INV_T (1.0f / 0.09f)
#define MOM   0.7f

// output layout (float32 elements, concatenated in return order)
#define OUT_LOGITS 0
#define OUT_LABELS (BB * LL)                    // 524288
#define OUT_QUEUE  (BB * LL + BB)               // 525312
#define OUT_PARAMK (BB * LL + BB + DIM * KCOLS) // 8913920

// ws layout (bytes)
#define WS_QT 0                         // bf16 queueT [KCOLS][DIM] = 16 MiB
#define WS_QN (KCOLS * DIM * 2)         // f32 normalized q [BB][DIM]
#define WS_KN (WS_QN + BB * DIM * 4)    // f32 normalized keys [BB][DIM]

__device__ inline unsigned short f32_to_bf16(float f) {
    uint32_t u = __float_as_uint(f);
    uint32_t r = (u + 0x7fffu + ((u >> 16) & 1u)) >> 16;
    return (unsigned short)r;
}

// one wave per row; rows 0..BB-1 = q -> qn (normalized), BB..2BB-1 = keys -> kn
__global__ void norm_kernel(const float* __restrict__ q,
                            const float* __restrict__ keys,
                            float* __restrict__ qn, float* __restrict__ kn) {
    int w    = threadIdx.x >> 6;
    int lane = threadIdx.x & 63;
    int row  = blockIdx.x * 4 + w;   // 0..2047
    const float* src;
    float* dst;
    int r;
    if (row < BB) { src = q;    dst = qn; r = row; }
    else          { src = keys; dst = kn; r = row - BB; }
    float2 v = *(const float2*)&src[r * DIM + lane * 2];
    float s  = v.x * v.x + v.y * v.y;
#pragma unroll
    for (int m = 32; m >= 1; m >>= 1) s += __shfl_xor(s, m, 64);
    float inv = 1.0f / sqrtf(s);
    float2 o  = {v.x * inv, v.y * inv};
    *(float2*)&dst[r * DIM + lane * 2] = o;
}

// new_param_k = MOM*param_k + (1-MOM)*param_q ; also writes labels (zeros)
__global__ void param_kernel(const float* __restrict__ pq,
                             const float* __restrict__ pk,
                             float* __restrict__ out) {
    int gid  = blockIdx.x * blockDim.x + threadIdx.x;
    float4 a = ((const float4*)pq)[gid];
    float4 b = ((const float4*)pk)[gid];
    float4 r;
    r.x = b.x * MOM + a.x * (1.0f - MOM);
    r.y = b.y * MOM + a.y * (1.0f - MOM);
    r.z = b.z * MOM + a.z * (1.0f - MOM);
    r.w = b.w * MOM + a.w * (1.0f - MOM);
    ((float4*)(out + OUT_PARAMK))[gid] = r;
    if (gid < BB) out[OUT_LABELS + gid] = 0.0f;
}

// Fused: read queue once; write new_queue (with circular kn overwrite) AND
// bf16 transposed qt[KCOLS][DIM] (from ORIGINAL queue values).
__global__ void queue_fused_kernel(const float* __restrict__ queue,
                                   const float* __restrict__ kn,
                                   const int* __restrict__ ptr_p,
                                   float* __restrict__ outq,
                                   unsigned short* __restrict__ qt) {
    __shared__ float tile[64][DIM + 1];  // [k][d], 33 KB
    int k0 = blockIdx.x * 64;
    int t  = threadIdx.x;
    int kk = t & 63, dq = t >> 6;  // dq 0..3
    int ptr   = ptr_p[0];
    int start = min(max(ptr, 0), KCOLS - BB);  // dynamic_update_slice clamp
    int k     = k0 + kk;
    bool inwin = (k >= start) && (k < start + BB);
#pragma unroll
    for (int i = 0; i < 32; ++i) {
        int d = i * 4 + dq;
        float v = queue[d * KCOLS + k];
        tile[kk][d] = v;                              // original value for qt
        float w = inwin ? kn[(k - start) * DIM + d] : v;
        outq[d * KCOLS + k] = w;                      // new_queue
    }
    __syncthreads();
    int lane16 = t & 15, kq = t >> 4;  // kq 0..15
#pragma unroll
    for (int ki = 0; ki < 4; ++ki) {
        int kl = kq + ki * 16;
#pragma unroll
        for (int seg = 0; seg < 4; ++seg) {
            int d0 = seg * 32 + lane16 * 2;
            uint32_t lo = (uint32_t)f32_to_bf16(tile[kl][d0]);
            uint32_t hi = (uint32_t)f32_to_bf16(tile[kl][d0 + 1]);
            *(uint32_t*)&qt[(size_t)(k0 + kl) * DIM + d0] = lo | (hi << 16);
        }
    }
}

// logits[b][l] = dot(qn[b], queueT[sample_idx[b][l]]) / T
// 4 lanes per dot: each wave computes 16 l concurrently; 2 shuffle steps.
__global__ void logits_kernel(const float* __restrict__ qn,
                              const unsigned short* __restrict__ qt,
                              const int* __restrict__ sidx,
                              float* __restrict__ out_logits) {
    int b    = blockIdx.y;
    int t    = threadIdx.x;
    int wave = t >> 6;       // 0..3
    int lane = t & 63;
    int quarter = lane & 3;  // which 32-dim chunk
    int lg      = lane >> 2; // 0..15: which l within the wave's group

    // load this lane's 32 q coefficients into registers
    float qreg[32];
    const float4* qb = (const float4*)(qn + b * DIM + quarter * 32);
#pragma unroll
    for (int i = 0; i < 8; ++i) {
        float4 v = qb[i];
        qreg[4 * i + 0] = v.x; qreg[4 * i + 1] = v.y;
        qreg[4 * i + 2] = v.z; qreg[4 * i + 3] = v.w;
    }

    int l = blockIdx.x * 64 + wave * 16 + lg;
    int idx = sidx[b * LL + l];
    const uint4* p = (const uint4*)(qt + (size_t)idx * DIM + quarter * 32);
    float s0 = 0.f, s1 = 0.f, s2 = 0.f, s3 = 0.f;
#pragma unroll
    for (int c = 0; c < 4; ++c) {
        uint4 u = p[c];
        float acc = 0.f;
        acc += qreg[c * 8 + 0] * __uint_as_float(u.x << 16);
        acc += qreg[c * 8 + 1] * __uint_as_float(u.x & 0xffff0000u);
        acc += qreg[c * 8 + 2] * __uint_as_float(u.y << 16);
        acc += qreg[c * 8 + 3] * __uint_as_float(u.y & 0xffff0000u);
        acc += qreg[c * 8 + 4] * __uint_as_float(u.z << 16);
        acc += qreg[c * 8 + 5] * __uint_as_float(u.z & 0xffff0000u);
        acc += qreg[c * 8 + 6] * __uint_as_float(u.w << 16);
        acc += qreg[c * 8 + 7] * __uint_as_float(u.w & 0xffff0000u);
        if (c == 0) s0 = acc; else if (c == 1) s1 = acc;
        else if (c == 2) s2 = acc; else s3 = acc;
    }
    float s = (s0 + s1) + (s2 + s3);
    s += __shfl_xor(s, 1, 64);
    s += __shfl_xor(s, 2, 64);
    if (quarter == 0) out_logits[b * LL + l] = s * INV_T;
}

extern "C" void kernel_launch(void* const* d_in, const int* in_sizes, int n_in,
                              void* d_out, int out_size, void* d_ws, size_t ws_size,
                              hipStream_t stream) {
    const float* q     = (const float*)d_in[0];
    const float* queue = (const float*)d_in[1];
    const float* keys  = (const float*)d_in[2];
    const float* pq    = (const float*)d_in[3];
    const float* pk    = (const float*)d_in[4];
    const int*   sidx  = (const int*)d_in[5];
    const int*   ptr_p = (const int*)d_in[6];
    float* out = (float*)d_out;

    unsigned short* ws_qt = (unsigned short*)((char*)d_ws + WS_QT);
    float* ws_qn = (float*)((char*)d_ws + WS_QN);
    float* ws_kn = (float*)((char*)d_ws + WS_KN);

    // 1) row norms: qn, kn
    norm_kernel<<<512, 256, 0, stream>>>(q, keys, ws_qn, ws_kn);
    // 2) fused queue copy/overwrite + bf16 transpose
    queue_fused_kernel<<<KCOLS / 64, 256, 0, stream>>>(queue, ws_kn, ptr_p,
                                                       out + OUT_QUEUE, ws_qt);
    // 3) momentum param update + labels
    param_kernel<<<PSZ / 4 / 256, 256, 0, stream>>>(pq, pk, out);
    // 4) gathered dot products
    logits_kernel<<<dim3(LL / 64, BB), 256, 0, stream>>>(ws_qn, ws_qt, sidx,
                                                         out + OUT_LOGITS);
}

// Round 3
// 213.058 us; speedup vs baseline: 1.1302x; 1.0019x over previous
//
#include <hip/hip_runtime.h>
#include <stdint.h>

#define DIM   128
#define KCOLS 65536
#define BB    1024
#define LL    512
#define PSZ   8388608
#define INV_T (1.0f / 0.09f)
#define MOM   0.7f

// output layout (float32 elements, concatenated in return order)
#define OUT_LOGITS 0
#define OUT_LABELS (BB * LL)                    // 524288
#define OUT_QUEUE  (BB * LL + BB)               // 525312
#define OUT_PARAMK (BB * LL + BB + DIM * KCOLS) // 8913920

// ws layout (bytes)
#define WS_QT 0                         // bf16 queueT [KCOLS][DIM] = 16 MiB
#define WS_QN (KCOLS * DIM * 2)         // f32 normalized q [BB][DIM]
#define WS_KN (WS_QN + BB * DIM * 4)    // f32 normalized keys [BB][DIM]

__device__ inline unsigned short f32_to_bf16(float f) {
    uint32_t u = __float_as_uint(f);
    uint32_t r = (u + 0x7fffu + ((u >> 16) & 1u)) >> 16;
    return (unsigned short)r;
}

// one wave per row; rows 0..BB-1 = q -> qn (normalized), BB..2BB-1 = keys -> kn
__global__ void norm_kernel(const float* __restrict__ q,
                            const float* __restrict__ keys,
                            float* __restrict__ qn, float* __restrict__ kn) {
    int w    = threadIdx.x >> 6;
    int lane = threadIdx.x & 63;
    int row  = blockIdx.x * 4 + w;   // 0..2047
    const float* src;
    float* dst;
    int r;
    if (row < BB) { src = q;    dst = qn; r = row; }
    else          { src = keys; dst = kn; r = row - BB; }
    float2 v = *(const float2*)&src[r * DIM + lane * 2];
    float s  = v.x * v.x + v.y * v.y;
#pragma unroll
    for (int m = 32; m >= 1; m >>= 1) s += __shfl_xor(s, m, 64);
    float inv = 1.0f / sqrtf(s);
    float2 o  = {v.x * inv, v.y * inv};
    *(float2*)&dst[r * DIM + lane * 2] = o;
}

// new_param_k = MOM*param_k + (1-MOM)*param_q ; also writes labels (zeros)
__global__ void param_kernel(const float* __restrict__ pq,
                             const float* __restrict__ pk,
                             float* __restrict__ out) {
    int gid  = blockIdx.x * blockDim.x + threadIdx.x;
    float4 a = ((const float4*)pq)[gid];
    float4 b = ((const float4*)pk)[gid];
    float4 r;
    r.x = b.x * MOM + a.x * (1.0f - MOM);
    r.y = b.y * MOM + a.y * (1.0f - MOM);
    r.z = b.z * MOM + a.z * (1.0f - MOM);
    r.w = b.w * MOM + a.w * (1.0f - MOM);
    ((float4*)(out + OUT_PARAMK))[gid] = r;
    if (gid < BB) out[OUT_LABELS + gid] = 0.0f;
}

// Fused: read queue once (float4-coalesced); write new_queue (float4) AND
// bf16 transposed qt[KCOLS][DIM] (uint4 rows), via LDS tile.
// Block = 64 k-columns x all 128 d-rows.
__global__ void queue_fused_kernel(const float* __restrict__ queue,
                                   const float* __restrict__ kn,
                                   const int* __restrict__ ptr_p,
                                   float* __restrict__ outq,
                                   unsigned short* __restrict__ qt) {
    __shared__ float tile[64][DIM + 1];  // [k][d], 33 KB
    int k0 = blockIdx.x * 64;
    int t  = threadIdx.x;
    int ptr   = ptr_p[0];
    int start = min(max(ptr, 0), KCOLS - BB);  // dynamic_update_slice clamp

    int lane16 = t & 15;
    int hi     = t >> 4;   // 0..15
    int kq     = lane16 * 4;   // column offset within tile, step 4
#pragma unroll
    for (int p = 0; p < 8; ++p) {
        int d = p * 16 + hi;
        float4 v = *(const float4*)&queue[(size_t)d * KCOLS + k0 + kq];
        float vv[4] = {v.x, v.y, v.z, v.w};
#pragma unroll
        for (int j = 0; j < 4; ++j) {
            tile[kq + j][d] = vv[j];           // original value for qt
            int col = k0 + kq + j;
            if (col >= start && col < start + BB)
                vv[j] = kn[(size_t)(col - start) * DIM + d];
        }
        float4 w = {vv[0], vv[1], vv[2], vv[3]};
        *(float4*)&outq[(size_t)d * KCOLS + k0 + kq] = w;
    }
    __syncthreads();
    // transpose out: each lane packs 8 consecutive d of one k-row -> uint4
    int d0 = lane16 * 8;
#pragma unroll
    for (int ki = 0; ki < 4; ++ki) {
        int kl = hi + ki * 16;  // 0..63
        float f[8];
#pragma unroll
        for (int j = 0; j < 8; ++j) f[j] = tile[kl][d0 + j];
        uint4 o;
        o.x = (uint32_t)f32_to_bf16(f[0]) | ((uint32_t)f32_to_bf16(f[1]) << 16);
        o.y = (uint32_t)f32_to_bf16(f[2]) | ((uint32_t)f32_to_bf16(f[3]) << 16);
        o.z = (uint32_t)f32_to_bf16(f[4]) | ((uint32_t)f32_to_bf16(f[5]) << 16);
        o.w = (uint32_t)f32_to_bf16(f[6]) | ((uint32_t)f32_to_bf16(f[7]) << 16);
        *(uint4*)&qt[(size_t)(k0 + kl) * DIM + d0] = o;
    }
}

// logits[b][l] = dot(qn[b], queueT[sample_idx[b][l]]) / T
// XCD-sharded: block (b, xcd) handles only idx with idx>>13 == xcd, so each
// XCD's L2 only ever caches its own 2 MB shard of qt (round-robin dispatch).
__global__ void __launch_bounds__(256)
logits_kernel(const float* __restrict__ qn,
              const unsigned short* __restrict__ qt,
              const int* __restrict__ sidx,
              float* __restrict__ out_logits) {
    int b   = blockIdx.x >> 3;
    int xcd = blockIdx.x & 7;
    int t   = threadIdx.x;

    __shared__ unsigned short lst[LL];
    __shared__ int n;
    if (t == 0) n = 0;
    __syncthreads();
#pragma unroll
    for (int l = t; l < LL; l += 256) {
        int idx = sidx[b * LL + l];
        if ((idx >> 13) == xcd) {
            int p = atomicAdd(&n, 1);
            lst[p] = (unsigned short)l;
        }
    }
    __syncthreads();
    int cnt = n;

    int quarter = t & 3;   // 32-dim chunk
    int grp     = t >> 2;  // 0..63: entry within pass

    // this lane's 32 q coefficients
    float qreg[32];
    const float4* qb = (const float4*)(qn + b * DIM + quarter * 32);
#pragma unroll
    for (int i = 0; i < 8; ++i) {
        float4 v = qb[i];
        qreg[4 * i + 0] = v.x; qreg[4 * i + 1] = v.y;
        qreg[4 * i + 2] = v.z; qreg[4 * i + 3] = v.w;
    }

    for (int i = grp; i < cnt; i += 64) {
        int l   = lst[i];
        int idx = sidx[b * LL + l];
        const uint4* p = (const uint4*)(qt + (size_t)idx * DIM + quarter * 32);
        float s0 = 0.f, s1 = 0.f, s2 = 0.f, s3 = 0.f;
#pragma unroll
        for (int c = 0; c < 4; ++c) {
            uint4 u = p[c];
            float acc = 0.f;
            acc += qreg[c * 8 + 0] * __uint_as_float(u.x << 16);
            acc += qreg[c * 8 + 1] * __uint_as_float(u.x & 0xffff0000u);
            acc += qreg[c * 8 + 2] * __uint_as_float(u.y << 16);
            acc += qreg[c * 8 + 3] * __uint_as_float(u.y & 0xffff0000u);
            acc += qreg[c * 8 + 4] * __uint_as_float(u.z << 16);
            acc += qreg[c * 8 + 5] * __uint_as_float(u.z & 0xffff0000u);
            acc += qreg[c * 8 + 6] * __uint_as_float(u.w << 16);
            acc += qreg[c * 8 + 7] * __uint_as_float(u.w & 0xffff0000u);
            if (c == 0) s0 = acc; else if (c == 1) s1 = acc;
            else if (c == 2) s2 = acc; else s3 = acc;
        }
        float s = (s0 + s1) + (s2 + s3);
        s += __shfl_xor(s, 1, 64);
        s += __shfl_xor(s, 2, 64);
        if (quarter == 0) out_logits[b * LL + l] = s * INV_T;
    }
}

extern "C" void kernel_launch(void* const* d_in, const int* in_sizes, int n_in,
                              void* d_out, int out_size, void* d_ws, size_t ws_size,
                              hipStream_t stream) {
    const float* q     = (const float*)d_in[0];
    const float* queue = (const float*)d_in[1];
    const float* keys  = (const float*)d_in[2];
    const float* pq    = (const float*)d_in[3];
    const float* pk    = (const float*)d_in[4];
    const int*   sidx  = (const int*)d_in[5];
    const int*   ptr_p = (const int*)d_in[6];
    float* out = (float*)d_out;

    unsigned short* ws_qt = (unsigned short*)((char*)d_ws + WS_QT);
    float* ws_qn = (float*)((char*)d_ws + WS_QN);
    float* ws_kn = (float*)((char*)d_ws + WS_KN);

    // 1) row norms: qn, kn
    norm_kernel<<<512, 256, 0, stream>>>(q, keys, ws_qn, ws_kn);
    // 2) fused queue copy/overwrite + bf16 transpose (coalesced)
    queue_fused_kernel<<<KCOLS / 64, 256, 0, stream>>>(queue, ws_kn, ptr_p,
                                                       out + OUT_QUEUE, ws_qt);
    // 3) momentum param update + labels
    param_kernel<<<PSZ / 4 / 256, 256, 0, stream>>>(pq, pk, out);
    // 4) gathered dot products, XCD-sharded
    logits_kernel<<<BB * 8, 256, 0, stream>>>(ws_qn, ws_qt, sidx,
                                              out + OUT_LOGITS);
}